// Round 13
// baseline (323.121 us; speedup 1.0000x reference)
//
#include <hip/hip_runtime.h>
#include <hip/hip_bf16.h>
#include <cstdint>

// Problem constants
#define BATCH   4
#define SEQ     1024
#define DM      512
#define NH      8
#define DH      64
#define RH      64

typedef float f32x4 __attribute__((ext_vector_type(4)));
typedef __bf16 bf16x8 __attribute__((ext_vector_type(8)));

// workspace byte offsets (ws is 256 MiB)
#define QB_OFF    (0)               // bf16 [B][NH][S][DH]   4 MB
#define KB_OFF    (4  << 20)        // bf16 [B][NH][S][DH]   4 MB
#define VT_OFF    (8  << 20)        // bf16 [B][NH][DH][S]   4 MB
#define XB_OFF    (12 << 20)        // bf16 [B*S][DM]        4 MB
#define WT_OFF    (16 << 20)        // bf16 [1536][512] (n,k) 1.5 MB
#define WOT_OFF   (18 << 20)        // bf16 [512][512]  (n,k) 0.5 MB
#define W2T_OFF   (19 << 20)        // bf16 [16][64] (h,k), rows 8..15 = 0
#define AW_OFF    (20 << 20)        // f32  [B*S][RH]        1 MB
#define CW_OFF    (21 << 20)        // f32  [B*S][RH]        1 MB
#define CTXB_OFF  (22 << 20)        // bf16 [B*S][DM]        4 MB
// bias, fragment-swizzled: [b][h][qt=64][wave=8][kc=4][r=16][rr=4][jt=8]
// per (b,h,qt): 16384 bf16 = 32 KB; total 64 MB
#define BIAS_OFF  (32 << 20)

// ---------------------------------------------------------------------------
// PROLOGUE (r10 version): cast_x / cast_w / rel+W2t, one launch.
// ---------------------------------------------------------------------------
__global__ __launch_bounds__(256) void prologue(
    const float* __restrict__ x,
    const float* __restrict__ Wq, const float* __restrict__ Wk,
    const float* __restrict__ Wv, const float* __restrict__ Wo,
    const float* __restrict__ freqs, const float* __restrict__ W1,
    const float* __restrict__ b1, const float* __restrict__ W2,
    __bf16* __restrict__ xb, __bf16* __restrict__ Wt,
    __bf16* __restrict__ Wot, float* __restrict__ Aw,
    float* __restrict__ Cw, __bf16* __restrict__ W2t)
{
    const int t = threadIdx.x;
    const int id = blockIdx.x;
    __shared__ __align__(16) float Ts[64][65];

    if (id < 1024) {
        const size_t i = ((size_t)id * 256 + t) * 8;
        const float4 a = *(const float4*)&x[i];
        const float4 b = *(const float4*)&x[i + 4];
        bf16x8 o;
        o[0] = (__bf16)a.x; o[1] = (__bf16)a.y; o[2] = (__bf16)a.z; o[3] = (__bf16)a.w;
        o[4] = (__bf16)b.x; o[5] = (__bf16)b.y; o[6] = (__bf16)b.z; o[7] = (__bf16)b.w;
        *(bf16x8*)&xb[i] = o;
    } else if (id < 1280) {
        const int lin = id - 1024;          // 0..255
        const int z   = lin >> 6;           // 0..3
        const int rem = lin & 63;
        const int k0  = (rem >> 3) * 64;
        const int n0  = (rem & 7) * 64;
        const float* __restrict__ src = (z == 0) ? Wq : (z == 1) ? Wk
                                       : (z == 2) ? Wv : Wo;
        __bf16* __restrict__ dst = (z < 3) ? (Wt + (size_t)(z * 512 + n0) * 512)
                                           : (Wot + (size_t)n0 * 512);
        #pragma unroll
        for (int i = 0; i < 4; ++i) {
            const int iid = t + i * 256;
            const int row = iid >> 4, c4 = (iid & 15) * 4;
            const float4 v = *(const float4*)&src[(size_t)(k0 + row) * DM + n0 + c4];
            Ts[row][c4 + 0] = v.x; Ts[row][c4 + 1] = v.y;
            Ts[row][c4 + 2] = v.z; Ts[row][c4 + 3] = v.w;
        }
        __syncthreads();
        #pragma unroll
        for (int i = 0; i < 2; ++i) {
            const int iid = t + i * 256;
            const int rn = iid >> 3, ck = (iid & 7) * 8;
            bf16x8 o;
            #pragma unroll
            for (int j = 0; j < 8; ++j) o[j] = (__bf16)Ts[ck + j][rn];
            *(bf16x8*)&dst[(size_t)rn * 512 + k0 + ck] = o;
        }
    } else {
        const int lin = id - 1280;          // 0..1023
        const int row = lin * 4 + (t >> 6);
        const int k = t & 63;
        const float f = freqs[row];
        const float L = logf(f + 1e-6f);
        const float base = f * W1[k] + L * W1[RH + k];
        Aw[(size_t)row * RH + k] = base + b1[k];
        Cw[(size_t)row * RH + k] = -base;
        if (row < 16)
            W2t[row * 64 + k] = (row < NH) ? (__bf16)W2[k * NH + row] : (__bf16)0.f;
    }
}

// ---------------------------------------------------------------------------
// MID (r10 structure): QKV GEMM (blocks 0..383) ∪ bias MLP (384..1407).
// bias MLP now stores into the fragment-swizzled bias layout (scatter
// stores: measured Δ0 in r7; overlapped with QKV here).
// ---------------------------------------------------------------------------
__global__ __launch_bounds__(256) void mid_fused(
    const __bf16* __restrict__ xb, const __bf16* __restrict__ Wt,
    const float* __restrict__ bq, const float* __restrict__ bk,
    const float* __restrict__ bv,
    __bf16* __restrict__ Qb, __bf16* __restrict__ Kb, __bf16* __restrict__ Vtb,
    const float* __restrict__ Aw, const float* __restrict__ Cw,
    const __bf16* __restrict__ W2t, __bf16* __restrict__ biasb)
{
    const int t = threadIdx.x;
    __shared__ __align__(16) char smem[36864];

    if (blockIdx.x < 384) {
        // ================= QKV GEMM =================
        const int wave = t >> 6, lane = t & 63;
        const int wm = wave >> 1, wn = wave & 1;
        const int r = lane & 15, kc = lane >> 4, q4 = kc * 4;
        const int lin = blockIdx.x;                              // 0..383
        const int swz = (lin & 7) * 48 + (lin >> 3);             // XCD-contiguous
        const int m0 = (swz / 12) * 128;
        const int n0 = (swz % 12) * 128;          // 0..1535
        const int sec = n0 >> 9;                  // 0=Q 1=K 2=V
        const int nn = n0 & 511;

        __bf16* __restrict__ As = (__bf16*)smem;            // [128][72]
        __bf16* __restrict__ Bs = (__bf16*)(smem + 18432);  // [128][72]

        f32x4 acc[4][4];
        #pragma unroll
        for (int i = 0; i < 4; ++i)
            #pragma unroll
            for (int j = 0; j < 4; ++j) acc[i][j] = {0.f, 0.f, 0.f, 0.f};

        const int srow = t >> 3, sck = (t & 7) * 8;
        const __bf16* __restrict__ Ag = xb + (size_t)(m0 + srow) * 512 + sck;
        const __bf16* __restrict__ Bg = Wt + (size_t)(n0 + srow) * 512 + sck;

        for (int k0 = 0; k0 < 512; k0 += 64) {
            bf16x8 ra[4], rb[4];
            #pragma unroll
            for (int i = 0; i < 4; ++i) {
                ra[i] = *(const bf16x8*)(Ag + (size_t)i * 32 * 512 + k0);
                rb[i] = *(const bf16x8*)(Bg + (size_t)i * 32 * 512 + k0);
            }
            __syncthreads();
            #pragma unroll
            for (int i = 0; i < 4; ++i) {
                *(bf16x8*)&As[(srow + i * 32) * 72 + sck] = ra[i];
                *(bf16x8*)&Bs[(srow + i * 32) * 72 + sck] = rb[i];
            }
            __syncthreads();
            #pragma unroll
            for (int ks = 0; ks < 2; ++ks) {
                bf16x8 af[4], bf[4];
                #pragma unroll
                for (int mf = 0; mf < 4; ++mf)
                    af[mf] = *(const bf16x8*)&As[(wm * 64 + mf * 16 + r) * 72 + ks * 32 + kc * 8];
                #pragma unroll
                for (int nf = 0; nf < 4; ++nf)
                    bf[nf] = *(const bf16x8*)&Bs[(wn * 64 + nf * 16 + r) * 72 + ks * 32 + kc * 8];
                #pragma unroll
                for (int mf = 0; mf < 4; ++mf)
                    #pragma unroll
                    for (int nf = 0; nf < 4; ++nf)
                        acc[mf][nf] = __builtin_amdgcn_mfma_f32_16x16x32_bf16(
                            af[mf], bf[nf], acc[mf][nf], 0, 0, 0);
            }
        }

        const float* __restrict__ bias = (sec == 0) ? bq : (sec == 1) ? bk : bv;
        __syncthreads();
        __bf16* __restrict__ Ls = (__bf16*)smem;            // [128][136]
        if (sec < 2) {
            #pragma unroll
            for (int mf = 0; mf < 4; ++mf)
                #pragma unroll
                for (int nf = 0; nf < 4; ++nf) {
                    const int n_l = wn * 64 + nf * 16 + r;
                    const float bb = bias[nn + n_l];
                    #pragma unroll
                    for (int rr = 0; rr < 4; ++rr)
                        Ls[(wm * 64 + mf * 16 + q4 + rr) * 136 + n_l] =
                            (__bf16)(acc[mf][nf][rr] + bb);
                }
        } else {
            #pragma unroll
            for (int mf = 0; mf < 4; ++mf)
                #pragma unroll
                for (int nf = 0; nf < 4; ++nf) {
                    const int n_l = wn * 64 + nf * 16 + r;
                    const float bb = bias[nn + n_l];
                    #pragma unroll
                    for (int rr = 0; rr < 4; ++rr)
                        Ls[n_l * 136 + (wm * 64 + mf * 16 + q4 + rr)] =
                            (__bf16)(acc[mf][nf][rr] + bb);
                }
        }
        __syncthreads();

        const int b = m0 >> 10, sbase = m0 & 1023;
        if (sec < 2) {
            __bf16* __restrict__ dst = sec ? Kb : Qb;
            #pragma unroll
            for (int i = 0; i < 8; ++i) {
                const int id = t + i * 256;
                const int row = id >> 4, nc = (id & 15) * 8;
                const bf16x8 v = *(const bf16x8*)&Ls[row * 136 + nc];
                const int ng = nn + nc, h = ng >> 6, c = ng & 63;
                *(bf16x8*)&dst[((size_t)(b * NH + h) * SEQ + sbase + row) * DH + c] = v;
            }
        } else {
            #pragma unroll
            for (int i = 0; i < 8; ++i) {
                const int id = t + i * 256;
                const int nrow = id >> 4, mc = (id & 15) * 8;
                const bf16x8 v = *(const bf16x8*)&Ls[nrow * 136 + mc];
                const int ng = nn + nrow, h = ng >> 6, c = ng & 63;
                *(bf16x8*)&Vtb[((size_t)(b * NH + h) * DH + c) * SEQ + sbase + mc] = v;
            }
        }
    } else {
        // ================= bias MLP v3 (fragment-swizzled output) ==========
        const int wave = t >> 6, lane = t & 63;
        const int il = lane & 15, kc = lane >> 4;
        const int id2 = blockIdx.x - 384;        // 0..1023
        const int b   = id2 >> 8;                // 0..3
        const int rem = id2 & 255;
        const int i0  = (rem >> 3) * 32;         // 0..992
        const int j0w = rem & 7;                 // j-block (128 j), = wave_a
        const int j0  = j0w * 128;

        float* __restrict__ Cs = (float*)smem;   // [128][68] = 34816 B

        {
            const int jr = t >> 1, half = (t & 1) * 32;
            const float* __restrict__ src = &Cw[((size_t)b * SEQ + j0 + jr) * RH + half];
            #pragma unroll
            for (int q = 0; q < 8; ++q)
                *(float4*)&Cs[jr * 68 + half + q * 4] = *(const float4*)(src + q * 4);
        }

        const bf16x8 w2f0 = *(const bf16x8*)&W2t[il * 64 + kc * 8];
        const bf16x8 w2f1 = *(const bf16x8*)&W2t[il * 64 + 32 + kc * 8];
        __syncthreads();

        #pragma unroll
        for (int ih = 0; ih < 2; ++ih) {
            const float* __restrict__ ap =
                &Aw[((size_t)b * SEQ + i0 + ih * 16 + il) * RH];
            const float4 a0 = *(const float4*)(ap + kc * 8);
            const float4 a1 = *(const float4*)(ap + kc * 8 + 4);
            const float4 a2 = *(const float4*)(ap + 32 + kc * 8);
            const float4 a3 = *(const float4*)(ap + 32 + kc * 8 + 4);

            // qt = i>>4 for all rows this wave produces (i0 mult of 32)
            const int qt = (i0 >> 4) + ih;
            // per-(b,h,qt,wave_a) base in fragment-swizzled layout
            __bf16* __restrict__ bout = (il < 8)
                ? (biasb + (((size_t)(b * NH + il) * 64 + qt) * 16384)
                   + (size_t)j0w * 4096)
                : nullptr;

            #pragma unroll
            for (int jb = 0; jb < 4; ++jb) {
                f32x4 accJ[8];
                #pragma unroll
                for (int jj = 0; jj < 8; ++jj) {
                    const float* __restrict__ cp =
                        &Cs[(wave * 32 + jb * 8 + jj) * 68 + kc * 8];
                    const float4 c0 = *(const float4*)(cp);
                    const float4 c1 = *(const float4*)(cp + 4);
                    const float4 c2 = *(const float4*)(cp + 32);
                    const float4 c3 = *(const float4*)(cp + 36);
                    bf16x8 hb0, hb1;
                    hb0[0] = (__bf16)fmaxf(a0.x + c0.x, 0.f);
                    hb0[1] = (__bf16)fmaxf(a0.y + c0.y, 0.f);
                    hb0[2] = (__bf16)fmaxf(a0.z + c0.z, 0.f);
                    hb0[3] = (__bf16)fmaxf(a0.w + c0.w, 0.f);
                    hb0[4] = (__bf16)fmaxf(a1.x + c1.x, 0.f);
                    hb0[5] = (__bf16)fmaxf(a1.y + c1.y, 0.f);
                    hb0[6] = (__bf16)fmaxf(a1.z + c1.z, 0.f);
                    hb0[7] = (__bf16)fmaxf(a1.w + c1.w, 0.f);
                    hb1[0] = (__bf16)fmaxf(a2.x + c2.x, 0.f);
                    hb1[1] = (__bf16)fmaxf(a2.y + c2.y, 0.f);
                    hb1[2] = (__bf16)fmaxf(a2.z + c2.z, 0.f);
                    hb1[3] = (__bf16)fmaxf(a2.w + c2.w, 0.f);
                    hb1[4] = (__bf16)fmaxf(a3.x + c3.x, 0.f);
                    hb1[5] = (__bf16)fmaxf(a3.y + c3.y, 0.f);
                    hb1[6] = (__bf16)fmaxf(a3.z + c3.z, 0.f);
                    hb1[7] = (__bf16)fmaxf(a3.w + c3.w, 0.f);
                    f32x4 acc = {0.f, 0.f, 0.f, 0.f};
                    acc = __builtin_amdgcn_mfma_f32_16x16x32_bf16(hb0, w2f0, acc, 0, 0, 0);
                    acc = __builtin_amdgcn_mfma_f32_16x16x32_bf16(hb1, w2f1, acc, 0, 0, 0);
                    accJ[jj] = acc;
                }
                // Fragment-swizzled scatter store:
                // elem (q=kc*4+rr, j=wave*32+jb*8+jj) ->
                //   off = (kc*16 + r_a)*32 + rr*8 + jt_a,
                //   jt_a = (wave*32+jb*8+jj)>>4, r_a = (wave*32+jb*8+jj)&15
                if (il < 8) {
                    #pragma unroll
                    for (int jj = 0; jj < 8; ++jj) {
                        const int within = wave * 32 + jb * 8 + jj;
                        const int jt_a = within >> 4, r_a = within & 15;
                        #pragma unroll
                        for (int rr = 0; rr < 4; ++rr)
                            bout[(kc * 16 + r_a) * 32 + rr * 8 + jt_a] =
                                (__bf16)accJ[jj][rr];
                    }
                }
            }
        }
    }
}

// ---------------------------------------------------------------------------
// MFMA attention (r8 core). Bias now loaded as 4x bf16x8 per thread from the
// fragment-swizzled layout: each thread's 32 bias values are one contiguous
// 64B run. VMEM instr/thread 48 -> 20; no LDS staging, no extra barrier.
// ---------------------------------------------------------------------------
#define PSTR 1032    // bf16 P row stride

__global__ __launch_bounds__(512) void attn_mfma(
    const __bf16* __restrict__ Qb, const __bf16* __restrict__ Kb,
    const __bf16* __restrict__ Vtb, const __bf16* __restrict__ biasb,
    __bf16* __restrict__ ctxb)
{
    const int t = threadIdx.x;
    const int wave = t >> 6, lane = t & 63;
    const int r = lane & 15, kc = lane >> 4;
    const int blk = (blockIdx.x & 7) * 256 + (blockIdx.x >> 3);  // XCD swizzle
    const int it = blk & 63;
    const int h  = (blk >> 6) & 7;
    const int b  = blk >> 9;
    const int s0 = it * 16;
    const int bh = b * NH + h;

    __shared__ __align__(16) __bf16 Pb[16 * PSTR];   // 33024 B
    __shared__ __align__(16) float part[1088];       // phase-3 partials
    __shared__ float red[8][16];
    __shared__ float invl[16];

    // ---- bias prefetch: contiguous 64B per thread (fragment-swizzled)
    bf16x8 brg8[4];
    {
        const __bf16* __restrict__ bb = biasb
            + (((size_t)bh * 64 + it) * 16384)
            + (size_t)wave * 4096 + (kc * 16 + r) * 32;
        #pragma unroll
        for (int q = 0; q < 4; ++q)
            brg8[q] = *(const bf16x8*)(bb + q * 8);
    }

    // ---- phase 1: QK^T via MFMA, scores stay in registers
    f32x4 sc[8];
    {
        const __bf16* __restrict__ Qp = Qb + ((size_t)bh * SEQ + s0) * DH;
        const __bf16* __restrict__ Kp = Kb + ((size_t)bh * SEQ + wave * 128) * DH;
        const bf16x8 qa0 = *(const bf16x8*)(Qp + r * DH + kc * 8);
        const bf16x8 qa1 = *(const bf16x8*)(Qp + r * DH + 32 + kc * 8);
        __builtin_amdgcn_s_setprio(1);
        #pragma unroll
        for (int jt = 0; jt < 8; ++jt) {
            const bf16x8 kb0 = *(const bf16x8*)(Kp + (size_t)(jt * 16 + r) * DH + kc * 8);
            const bf16x8 kb1 = *(const bf16x8*)(Kp + (size_t)(jt * 16 + r) * DH + 32 + kc * 8);
            f32x4 a = {0.f, 0.f, 0.f, 0.f};
            a = __builtin_amdgcn_mfma_f32_16x16x32_bf16(qa0, kb0, a, 0, 0, 0);
            a = __builtin_amdgcn_mfma_f32_16x16x32_bf16(qa1, kb1, a, 0, 0, 0);
            sc[jt] = a;
        }
        __builtin_amdgcn_s_setprio(0);
    }

    // ---- phase 1.5: bias add + exp (no-max) + per-row partial sums
    float psum[4] = {0.f, 0.f, 0.f, 0.f};
    #pragma unroll
    for (int jt = 0; jt < 8; ++jt) {
        #pragma unroll
        for (int rr = 0; rr < 4; ++rr) {
            const float s = fmaf(sc[jt][rr], 0.125f, (float)brg8[rr][jt]);
            const float p = __expf(fminf(s, 30.f));
            sc[jt][rr] = p;
            psum[rr] += p;
        }
    }
    // reduce across the 16 lanes (r) of each kc group
    #pragma unroll
    for (int mask = 8; mask >= 1; mask >>= 1)
        #pragma unroll
        for (int rr = 0; rr < 4; ++rr)
            psum[rr] += __shfl_xor(psum[rr], mask);
    if (r == 0) {
        #pragma unroll
        for (int rr = 0; rr < 4; ++rr) red[wave][kc * 4 + rr] = psum[rr];
    }
    // write un-normalized P (bf16) to LDS
    #pragma unroll
    for (int jt = 0; jt < 8; ++jt)
        #pragma unroll
        for (int rr = 0; rr < 4; ++rr)
            Pb[(kc * 4 + rr) * PSTR + wave * 128 + jt * 16 + r] = (__bf16)sc[jt][rr];
    __syncthreads();

    if (t < 16) {
        float l = 0.f;
        #pragma unroll
        for (int w = 0; w < 8; ++w) l += red[w][t];
        invl[t] = 1.0f / l;
    }

    // ---- phase 3: P @ V ; wave = (c-tile = wave&3, K-half = wave>>2)
    {
        const int ct = wave & 3, kh = wave >> 2;
        const __bf16* __restrict__ Vp =
            Vtb + ((size_t)bh * DH + ct * 16 + r) * SEQ + kh * 512;
        f32x4 acc = {0.f, 0.f, 0.f, 0.f};
        __builtin_amdgcn_s_setprio(1);
        #pragma unroll 4
        for (int jt = 0; jt < 16; ++jt) {
            const bf16x8 pa = *(const bf16x8*)&Pb[r * PSTR + kh * 512 + jt * 32 + kc * 8];
            const bf16x8 vb = *(const bf16x8*)(Vp + jt * 32 + kc * 8);
            acc = __builtin_amdgcn_mfma_f32_16x16x32_bf16(pa, vb, acc, 0, 0, 0);
        }
        __builtin_amdgcn_s_setprio(0);
        if (kh == 1) {
            #pragma unroll
            for (int rr = 0; rr < 4; ++rr)
                part[ct * 272 + (kc * 4 + rr) * 17 + r] = acc[rr];
        }
        __syncthreads();
        if (kh == 0) {
            #pragma unroll
            for (int rr = 0; rr < 4; ++rr) {
                const int row = kc * 4 + rr;
                const float v = (acc[rr] + part[ct * 272 + row * 17 + r]) * invl[row];
                ctxb[((size_t)(b * SEQ) + s0 + row) * DM + h * DH + ct * 16 + r] = (__bf16)v;
            }
        }
    }
}

// ---------------------------------------------------------------------------
// MFMA GEMM (out) — r10 version (precomputed Wot). 128 blocks.
// ---------------------------------------------------------------------------
__global__ __launch_bounds__(256) void gemm_out_mfma(
    const __bf16* __restrict__ ctxb, const __bf16* __restrict__ Wot,
    const float* __restrict__ bo, float* __restrict__ out)
{
    const int t = threadIdx.x;
    const int wave = t >> 6, lane = t & 63;
    const int wm = wave >> 1, wn = wave & 1;
    const int r = lane & 15, kc = lane >> 4, q4 = kc * 4;
    const int lin = blockIdx.y * 4 + blockIdx.x;             // 0..127
    const int swz = (lin & 7) * 16 + (lin >> 3);
    const int m0 = (swz / 4) * 128;
    const int n0 = (swz % 4) * 128;

    __shared__ __align__(16) char smem[36864];
    __bf16* __restrict__ As = (__bf16*)smem;
    __bf16* __restrict__ Bs = (__bf16*)(smem + 18432);

    f32x4 acc[4][4];
    #pragma unroll
    for (int i = 0; i < 4; ++i)
        #pragma unroll
        for (int j = 0; j < 4; ++j) acc[i][j] = {0.f, 0.f, 0.f, 0.f};

    const int srow = t >> 3, sck = (t & 7) * 8;
    const __bf16* __restrict__ Ag = ctxb + (size_t)(m0 + srow) * 512 + sck;
    const __bf16* __restrict__ Bg = Wot + (size_t)(n0 + srow) * 512 + sck;

    for (int k0 = 0; k0 < 512; k0 += 64) {
        bf16x8 ra[4], rb[4];
        #pragma unroll
        for (int i = 0; i < 4; ++i) {
            ra[i] = *(const bf16x8*)(Ag + (size_t)i * 32 * 512 + k0);
            rb[i] = *(const bf16x8*)(Bg + (size_t)i * 32 * 512 + k0);
        }
        __syncthreads();
        #pragma unroll
        for (int i = 0; i < 4; ++i) {
            *(bf16x8*)&As[(srow + i * 32) * 72 + sck] = ra[i];
            *(bf16x8*)&Bs[(srow + i * 32) * 72 + sck] = rb[i];
        }
        __syncthreads();
        #pragma unroll
        for (int ks = 0; ks < 2; ++ks) {
            bf16x8 af[4], bf[4];
            #pragma unroll
            for (int mf = 0; mf < 4; ++mf)
                af[mf] = *(const bf16x8*)&As[(wm * 64 + mf * 16 + r) * 72 + ks * 32 + kc * 8];
            #pragma unroll
            for (int nf = 0; nf < 4; ++nf)
                bf[nf] = *(const bf16x8*)&Bs[(wn * 64 + nf * 16 + r) * 72 + ks * 32 + kc * 8];
            #pragma unroll
            for (int mf = 0; mf < 4; ++mf)
                #pragma unroll
                for (int nf = 0; nf < 4; ++nf)
                    acc[mf][nf] = __builtin_amdgcn_mfma_f32_16x16x32_bf16(
                        af[mf], bf[nf], acc[mf][nf], 0, 0, 0);
        }
    }

    #pragma unroll
    for (int mf = 0; mf < 4; ++mf)
        #pragma unroll
        for (int nf = 0; nf < 4; ++nf) {
            const int n_l = wn * 64 + nf * 16 + r;
            const float bb = bo[n0 + n_l];
            #pragma unroll
            for (int rr = 0; rr < 4; ++rr)
                out[(size_t)(m0 + wm * 64 + mf * 16 + q4 + rr) * DM + n0 + n_l] =
                    acc[mf][nf][rr] + bb;
        }
}

// ---------------------------------------------------------------------------
extern "C" void kernel_launch(void* const* d_in, const int* in_sizes, int n_in,
                              void* d_out, int out_size, void* d_ws, size_t ws_size,
                              hipStream_t stream)
{
    const float* x     = (const float*)d_in[0];
    const float* freqs = (const float*)d_in[1];
    const float* Wq    = (const float*)d_in[2];
    const float* bq    = (const float*)d_in[3];
    const float* Wk    = (const float*)d_in[4];
    const float* bk    = (const float*)d_in[5];
    const float* Wv    = (const float*)d_in[6];
    const float* bv    = (const float*)d_in[7];
    const float* Wo    = (const float*)d_in[8];
    const float* bo    = (const float*)d_in[9];
    const float* W1    = (const float*)d_in[10];
    const float* b1    = (const float*)d_in[11];
    const float* W2    = (const float*)d_in[12];
    // b2 (d_in[13]) is softmax-invariant: dropped.

    char* wsb = (char*)d_ws;
    __bf16* Qb    = (__bf16*)(wsb + QB_OFF);
    __bf16* Kb    = (__bf16*)(wsb + KB_OFF);
    __bf16* Vtb   = (__bf16*)(wsb + VT_OFF);
    __bf16* xb    = (__bf16*)(wsb + XB_OFF);
    __bf16* Wt    = (__bf16*)(wsb + WT_OFF);
    __bf16* Wot   = (__bf16*)(wsb + WOT_OFF);
    __bf16* W2t   = (__bf16*)(wsb + W2T_OFF);
    float*  Aw    = (float*)(wsb + AW_OFF);
    float*  Cw    = (float*)(wsb + CW_OFF);
    __bf16* ctxb  = (__bf16*)(wsb + CTXB_OFF);
    __bf16* biasb = (__bf16*)(wsb + BIAS_OFF);
    float* out = (float*)d_out;

    prologue<<<dim3(2304), 256, 0, stream>>>(
        x, Wq, Wk, Wv, Wo, freqs, W1, b1, W2, xb, Wt, Wot, Aw, Cw, W2t);
    mid_fused<<<dim3(1408), 256, 0, stream>>>(
        xb, Wt, bq, bk, bv, Qb, Kb, Vtb, Aw, Cw, W2t, biasb);
    attn_mfma<<<dim3(2048), 512, 0, stream>>>(Qb, Kb, Vtb, biasb, ctxb);
    gemm_out_mfma<<<dim3(4, 32), 256, 0, stream>>>(ctxb, Wot, bo, out);
}

// Round 14
// 207.752 us; speedup vs baseline: 1.5553x; 1.5553x over previous
//
#include <hip/hip_runtime.h>
#include <hip/hip_bf16.h>
#include <cstdint>

// Problem constants
#define BATCH   4
#define SEQ     1024
#define DM      512
#define NH      8
#define DH      64
#define RH      64

typedef float f32x4 __attribute__((ext_vector_type(4)));
typedef __bf16 bf16x8 __attribute__((ext_vector_type(8)));

// workspace byte offsets (ws is 256 MiB)
#define QB_OFF    (0)               // bf16 [B][NH][S][DH]   4 MB
#define KB_OFF    (4  << 20)        // bf16 [B][NH][S][DH]   4 MB
#define VT_OFF    (8  << 20)        // bf16 [B][NH][DH][S]   4 MB
#define XB_OFF    (12 << 20)        // bf16 [B*S][DM]        4 MB
#define WT_OFF    (16 << 20)        // bf16 [1536][512] (n,k) 1.5 MB
#define WOT_OFF   (18 << 20)        // bf16 [512][512]  (n,k) 0.5 MB
#define W2T_OFF   (19 << 20)        // bf16 [16][64] (h,k), rows 8..15 = 0
#define AW_OFF    (20 << 20)        // f32  [B*S][RH]        1 MB
#define CW_OFF    (21 << 20)        // f32  [B*S][RH]        1 MB
#define CTXB_OFF  (22 << 20)        // bf16 [B*S][DM]        4 MB
#define BIAS_OFF  (32 << 20)        // bf16 [B][NH][S][S]   64 MB

// ---------------------------------------------------------------------------
// PROLOGUE (r10): cast_x / cast_w / rel+W2t, one launch.
// ---------------------------------------------------------------------------
__global__ __launch_bounds__(256) void prologue(
    const float* __restrict__ x,
    const float* __restrict__ Wq, const float* __restrict__ Wk,
    const float* __restrict__ Wv, const float* __restrict__ Wo,
    const float* __restrict__ freqs, const float* __restrict__ W1,
    const float* __restrict__ b1, const float* __restrict__ W2,
    __bf16* __restrict__ xb, __bf16* __restrict__ Wt,
    __bf16* __restrict__ Wot, float* __restrict__ Aw,
    float* __restrict__ Cw, __bf16* __restrict__ W2t)
{
    const int t = threadIdx.x;
    const int id = blockIdx.x;
    __shared__ __align__(16) float Ts[64][65];

    if (id < 1024) {
        const size_t i = ((size_t)id * 256 + t) * 8;
        const float4 a = *(const float4*)&x[i];
        const float4 b = *(const float4*)&x[i + 4];
        bf16x8 o;
        o[0] = (__bf16)a.x; o[1] = (__bf16)a.y; o[2] = (__bf16)a.z; o[3] = (__bf16)a.w;
        o[4] = (__bf16)b.x; o[5] = (__bf16)b.y; o[6] = (__bf16)b.z; o[7] = (__bf16)b.w;
        *(bf16x8*)&xb[i] = o;
    } else if (id < 1280) {
        const int lin = id - 1024;          // 0..255
        const int z   = lin >> 6;           // 0..3
        const int rem = lin & 63;
        const int k0  = (rem >> 3) * 64;
        const int n0  = (rem & 7) * 64;
        const float* __restrict__ src = (z == 0) ? Wq : (z == 1) ? Wk
                                       : (z == 2) ? Wv : Wo;
        __bf16* __restrict__ dst = (z < 3) ? (Wt + (size_t)(z * 512 + n0) * 512)
                                           : (Wot + (size_t)n0 * 512);
        #pragma unroll
        for (int i = 0; i < 4; ++i) {
            const int iid = t + i * 256;
            const int row = iid >> 4, c4 = (iid & 15) * 4;
            const float4 v = *(const float4*)&src[(size_t)(k0 + row) * DM + n0 + c4];
            Ts[row][c4 + 0] = v.x; Ts[row][c4 + 1] = v.y;
            Ts[row][c4 + 2] = v.z; Ts[row][c4 + 3] = v.w;
        }
        __syncthreads();
        #pragma unroll
        for (int i = 0; i < 2; ++i) {
            const int iid = t + i * 256;
            const int rn = iid >> 3, ck = (iid & 7) * 8;
            bf16x8 o;
            #pragma unroll
            for (int j = 0; j < 8; ++j) o[j] = (__bf16)Ts[ck + j][rn];
            *(bf16x8*)&dst[(size_t)rn * 512 + k0 + ck] = o;
        }
    } else {
        const int lin = id - 1280;          // 0..1023
        const int row = lin * 4 + (t >> 6);
        const int k = t & 63;
        const float f = freqs[row];
        const float L = logf(f + 1e-6f);
        const float base = f * W1[k] + L * W1[RH + k];
        Aw[(size_t)row * RH + k] = base + b1[k];
        Cw[(size_t)row * RH + k] = -base;
        if (row < 16)
            W2t[row * 64 + k] = (row < NH) ? (__bf16)W2[k * NH + row] : (__bf16)0.f;
    }
}

// ---------------------------------------------------------------------------
// MID (r10): QKV GEMM (blocks 0..383) ∪ bias MLP (384..1407), coalesced
// bias output layout [b][h][i][j].
// ---------------------------------------------------------------------------
__global__ __launch_bounds__(256) void mid_fused(
    const __bf16* __restrict__ xb, const __bf16* __restrict__ Wt,
    const float* __restrict__ bq, const float* __restrict__ bk,
    const float* __restrict__ bv,
    __bf16* __restrict__ Qb, __bf16* __restrict__ Kb, __bf16* __restrict__ Vtb,
    const float* __restrict__ Aw, const float* __restrict__ Cw,
    const __bf16* __restrict__ W2t, __bf16* __restrict__ biasb)
{
    const int t = threadIdx.x;
    __shared__ __align__(16) char smem[36864];

    if (blockIdx.x < 384) {
        // ================= QKV GEMM =================
        const int wave = t >> 6, lane = t & 63;
        const int wm = wave >> 1, wn = wave & 1;
        const int r = lane & 15, kc = lane >> 4, q4 = kc * 4;
        const int lin = blockIdx.x;                              // 0..383
        const int swz = (lin & 7) * 48 + (lin >> 3);             // XCD-contiguous
        const int m0 = (swz / 12) * 128;
        const int n0 = (swz % 12) * 128;          // 0..1535
        const int sec = n0 >> 9;                  // 0=Q 1=K 2=V
        const int nn = n0 & 511;

        __bf16* __restrict__ As = (__bf16*)smem;            // [128][72]
        __bf16* __restrict__ Bs = (__bf16*)(smem + 18432);  // [128][72]

        f32x4 acc[4][4];
        #pragma unroll
        for (int i = 0; i < 4; ++i)
            #pragma unroll
            for (int j = 0; j < 4; ++j) acc[i][j] = {0.f, 0.f, 0.f, 0.f};

        const int srow = t >> 3, sck = (t & 7) * 8;
        const __bf16* __restrict__ Ag = xb + (size_t)(m0 + srow) * 512 + sck;
        const __bf16* __restrict__ Bg = Wt + (size_t)(n0 + srow) * 512 + sck;

        for (int k0 = 0; k0 < 512; k0 += 64) {
            bf16x8 ra[4], rb[4];
            #pragma unroll
            for (int i = 0; i < 4; ++i) {
                ra[i] = *(const bf16x8*)(Ag + (size_t)i * 32 * 512 + k0);
                rb[i] = *(const bf16x8*)(Bg + (size_t)i * 32 * 512 + k0);
            }
            __syncthreads();
            #pragma unroll
            for (int i = 0; i < 4; ++i) {
                *(bf16x8*)&As[(srow + i * 32) * 72 + sck] = ra[i];
                *(bf16x8*)&Bs[(srow + i * 32) * 72 + sck] = rb[i];
            }
            __syncthreads();
            #pragma unroll
            for (int ks = 0; ks < 2; ++ks) {
                bf16x8 af[4], bf[4];
                #pragma unroll
                for (int mf = 0; mf < 4; ++mf)
                    af[mf] = *(const bf16x8*)&As[(wm * 64 + mf * 16 + r) * 72 + ks * 32 + kc * 8];
                #pragma unroll
                for (int nf = 0; nf < 4; ++nf)
                    bf[nf] = *(const bf16x8*)&Bs[(wn * 64 + nf * 16 + r) * 72 + ks * 32 + kc * 8];
                #pragma unroll
                for (int mf = 0; mf < 4; ++mf)
                    #pragma unroll
                    for (int nf = 0; nf < 4; ++nf)
                        acc[mf][nf] = __builtin_amdgcn_mfma_f32_16x16x32_bf16(
                            af[mf], bf[nf], acc[mf][nf], 0, 0, 0);
            }
        }

        const float* __restrict__ bias = (sec == 0) ? bq : (sec == 1) ? bk : bv;
        __syncthreads();
        __bf16* __restrict__ Ls = (__bf16*)smem;            // [128][136]
        if (sec < 2) {
            #pragma unroll
            for (int mf = 0; mf < 4; ++mf)
                #pragma unroll
                for (int nf = 0; nf < 4; ++nf) {
                    const int n_l = wn * 64 + nf * 16 + r;
                    const float bb = bias[nn + n_l];
                    #pragma unroll
                    for (int rr = 0; rr < 4; ++rr)
                        Ls[(wm * 64 + mf * 16 + q4 + rr) * 136 + n_l] =
                            (__bf16)(acc[mf][nf][rr] + bb);
                }
        } else {
            #pragma unroll
            for (int mf = 0; mf < 4; ++mf)
                #pragma unroll
                for (int nf = 0; nf < 4; ++nf) {
                    const int n_l = wn * 64 + nf * 16 + r;
                    const float bb = bias[nn + n_l];
                    #pragma unroll
                    for (int rr = 0; rr < 4; ++rr)
                        Ls[n_l * 136 + (wm * 64 + mf * 16 + q4 + rr)] =
                            (__bf16)(acc[mf][nf][rr] + bb);
                }
        }
        __syncthreads();

        const int b = m0 >> 10, sbase = m0 & 1023;
        if (sec < 2) {
            __bf16* __restrict__ dst = sec ? Kb : Qb;
            #pragma unroll
            for (int i = 0; i < 8; ++i) {
                const int id = t + i * 256;
                const int row = id >> 4, nc = (id & 15) * 8;
                const bf16x8 v = *(const bf16x8*)&Ls[row * 136 + nc];
                const int ng = nn + nc, h = ng >> 6, c = ng & 63;
                *(bf16x8*)&dst[((size_t)(b * NH + h) * SEQ + sbase + row) * DH + c] = v;
            }
        } else {
            #pragma unroll
            for (int i = 0; i < 8; ++i) {
                const int id = t + i * 256;
                const int nrow = id >> 4, mc = (id & 15) * 8;
                const bf16x8 v = *(const bf16x8*)&Ls[nrow * 136 + mc];
                const int ng = nn + nrow, h = ng >> 6, c = ng & 63;
                *(bf16x8*)&Vtb[((size_t)(b * NH + h) * DH + c) * SEQ + sbase + mc] = v;
            }
        }
    } else {
        // ================= bias MLP v3 (coalesced bf16x8 output) ==========
        const int wave = t >> 6, lane = t & 63;
        const int il = lane & 15, kc = lane >> 4;
        const int id2 = blockIdx.x - 384;        // 0..1023
        const int b   = id2 >> 8;                // 0..3
        const int rem = id2 & 255;
        const int i0  = (rem >> 3) * 32;         // 0..992
        const int j0  = (rem & 7) * 128;         // 0..896

        float* __restrict__ Cs = (float*)smem;   // [128][68] = 34816 B

        {
            const int jr = t >> 1, half = (t & 1) * 32;
            const float* __restrict__ src = &Cw[((size_t)b * SEQ + j0 + jr) * RH + half];
            #pragma unroll
            for (int q = 0; q < 8; ++q)
                *(float4*)&Cs[jr * 68 + half + q * 4] = *(const float4*)(src + q * 4);
        }

        const bf16x8 w2f0 = *(const bf16x8*)&W2t[il * 64 + kc * 8];
        const bf16x8 w2f1 = *(const bf16x8*)&W2t[il * 64 + 32 + kc * 8];
        __syncthreads();

        #pragma unroll
        for (int ih = 0; ih < 2; ++ih) {
            const float* __restrict__ ap =
                &Aw[((size_t)b * SEQ + i0 + ih * 16 + il) * RH];
            const float4 a0 = *(const float4*)(ap + kc * 8);
            const float4 a1 = *(const float4*)(ap + kc * 8 + 4);
            const float4 a2 = *(const float4*)(ap + 32 + kc * 8);
            const float4 a3 = *(const float4*)(ap + 32 + kc * 8 + 4);

            #pragma unroll
            for (int jb = 0; jb < 4; ++jb) {
                f32x4 accJ[8];
                #pragma unroll
                for (int jj = 0; jj < 8; ++jj) {
                    const float* __restrict__ cp =
                        &Cs[(wave * 32 + jb * 8 + jj) * 68 + kc * 8];
                    const float4 c0 = *(const float4*)(cp);
                    const float4 c1 = *(const float4*)(cp + 4);
                    const float4 c2 = *(const float4*)(cp + 32);
                    const float4 c3 = *(const float4*)(cp + 36);
                    bf16x8 hb0, hb1;
                    hb0[0] = (__bf16)fmaxf(a0.x + c0.x, 0.f);
                    hb0[1] = (__bf16)fmaxf(a0.y + c0.y, 0.f);
                    hb0[2] = (__bf16)fmaxf(a0.z + c0.z, 0.f);
                    hb0[3] = (__bf16)fmaxf(a0.w + c0.w, 0.f);
                    hb0[4] = (__bf16)fmaxf(a1.x + c1.x, 0.f);
                    hb0[5] = (__bf16)fmaxf(a1.y + c1.y, 0.f);
                    hb0[6] = (__bf16)fmaxf(a1.z + c1.z, 0.f);
                    hb0[7] = (__bf16)fmaxf(a1.w + c1.w, 0.f);
                    hb1[0] = (__bf16)fmaxf(a2.x + c2.x, 0.f);
                    hb1[1] = (__bf16)fmaxf(a2.y + c2.y, 0.f);
                    hb1[2] = (__bf16)fmaxf(a2.z + c2.z, 0.f);
                    hb1[3] = (__bf16)fmaxf(a2.w + c2.w, 0.f);
                    hb1[4] = (__bf16)fmaxf(a3.x + c3.x, 0.f);
                    hb1[5] = (__bf16)fmaxf(a3.y + c3.y, 0.f);
                    hb1[6] = (__bf16)fmaxf(a3.z + c3.z, 0.f);
                    hb1[7] = (__bf16)fmaxf(a3.w + c3.w, 0.f);
                    f32x4 acc = {0.f, 0.f, 0.f, 0.f};
                    acc = __builtin_amdgcn_mfma_f32_16x16x32_bf16(hb0, w2f0, acc, 0, 0, 0);
                    acc = __builtin_amdgcn_mfma_f32_16x16x32_bf16(hb1, w2f1, acc, 0, 0, 0);
                    accJ[jj] = acc;
                }
                if (il < 8) {
                    #pragma unroll
                    for (int rr = 0; rr < 4; ++rr) {
                        bf16x8 pv;
                        #pragma unroll
                        for (int jj = 0; jj < 8; ++jj)
                            pv[jj] = (__bf16)accJ[jj][rr];
                        *(bf16x8*)&biasb[(((size_t)b * NH + il) * SEQ
                                          + i0 + ih * 16 + kc * 4 + rr) * SEQ
                                         + j0 + wave * 32 + jb * 8] = pv;
                    }
                }
            }
        }
    }
}

// ---------------------------------------------------------------------------
// MFMA attention (r8 core, best measured 72.0 us — unchanged from r10).
// ---------------------------------------------------------------------------
#define PSTR 1032    // bf16 P row stride

__global__ __launch_bounds__(512) void attn_mfma(
    const __bf16* __restrict__ Qb, const __bf16* __restrict__ Kb,
    const __bf16* __restrict__ Vtb, const __bf16* __restrict__ biasb,
    __bf16* __restrict__ ctxb)
{
    const int t = threadIdx.x;
    const int wave = t >> 6, lane = t & 63;
    const int r = lane & 15, kc = lane >> 4;
    const int blk = (blockIdx.x & 7) * 256 + (blockIdx.x >> 3);  // XCD swizzle
    const int it = blk & 63;
    const int h  = (blk >> 6) & 7;
    const int b  = blk >> 9;
    const int s0 = it * 16;
    const int bh = b * NH + h;

    __shared__ __align__(16) __bf16 Pb[16 * PSTR];   // 33024 B
    __shared__ __align__(16) float part[1088];       // phase-3 partials
    __shared__ float red[8][16];
    __shared__ float invl[16];

    // ---- bias prefetch, fragment layout: (row kc*4+rr, col wave*128+jt*16+r)
    uint32_t brg[4][8];
    {
        const uint16_t* __restrict__ bb = (const uint16_t*)biasb
            + ((size_t)bh * SEQ + s0 + kc * 4) * SEQ + wave * 128 + r;
        #pragma unroll
        for (int rr = 0; rr < 4; ++rr)
            #pragma unroll
            for (int jt = 0; jt < 8; ++jt)
                brg[rr][jt] = bb[(size_t)rr * SEQ + jt * 16];
    }

    // ---- phase 1: QK^T via MFMA, scores stay in registers
    f32x4 sc[8];
    {
        const __bf16* __restrict__ Qp = Qb + ((size_t)bh * SEQ + s0) * DH;
        const __bf16* __restrict__ Kp = Kb + ((size_t)bh * SEQ + wave * 128) * DH;
        const bf16x8 qa0 = *(const bf16x8*)(Qp + r * DH + kc * 8);
        const bf16x8 qa1 = *(const bf16x8*)(Qp + r * DH + 32 + kc * 8);
        __builtin_amdgcn_s_setprio(1);
        #pragma unroll
        for (int jt = 0; jt < 8; ++jt) {
            const bf16x8 kb0 = *(const bf16x8*)(Kp + (size_t)(jt * 16 + r) * DH + kc * 8);
            const bf16x8 kb1 = *(const bf16x8*)(Kp + (size_t)(jt * 16 + r) * DH + 32 + kc * 8);
            f32x4 a = {0.f, 0.f, 0.f, 0.f};
            a = __builtin_amdgcn_mfma_f32_16x16x32_bf16(qa0, kb0, a, 0, 0, 0);
            a = __builtin_amdgcn_mfma_f32_16x16x32_bf16(qa1, kb1, a, 0, 0, 0);
            sc[jt] = a;
        }
        __builtin_amdgcn_s_setprio(0);
    }

    // ---- phase 1.5: bias add + exp (no-max) + per-row partial sums
    float psum[4] = {0.f, 0.f, 0.f, 0.f};
    #pragma unroll
    for (int jt = 0; jt < 8; ++jt) {
        #pragma unroll
        for (int rr = 0; rr < 4; ++rr) {
            const float s = fmaf(sc[jt][rr], 0.125f,
                                 __uint_as_float(brg[rr][jt] << 16));
            const float p = __expf(fminf(s, 30.f));
            sc[jt][rr] = p;
            psum[rr] += p;
        }
    }
    // reduce across the 16 lanes (r) of each kc group
    #pragma unroll
    for (int mask = 8; mask >= 1; mask >>= 1)
        #pragma unroll
        for (int rr = 0; rr < 4; ++rr)
            psum[rr] += __shfl_xor(psum[rr], mask);
    if (r == 0) {
        #pragma unroll
        for (int rr = 0; rr < 4; ++rr) red[wave][kc * 4 + rr] = psum[rr];
    }
    // write un-normalized P (bf16) to LDS
    #pragma unroll
    for (int jt = 0; jt < 8; ++jt)
        #pragma unroll
        for (int rr = 0; rr < 4; ++rr)
            Pb[(kc * 4 + rr) * PSTR + wave * 128 + jt * 16 + r] = (__bf16)sc[jt][rr];
    __syncthreads();

    if (t < 16) {
        float l = 0.f;
        #pragma unroll
        for (int w = 0; w < 8; ++w) l += red[w][t];
        invl[t] = 1.0f / l;
    }

    // ---- phase 3: P @ V ; wave = (c-tile = wave&3, K-half = wave>>2)
    {
        const int ct = wave & 3, kh = wave >> 2;
        const __bf16* __restrict__ Vp =
            Vtb + ((size_t)bh * DH + ct * 16 + r) * SEQ + kh * 512;
        f32x4 acc = {0.f, 0.f, 0.f, 0.f};
        __builtin_amdgcn_s_setprio(1);
        #pragma unroll 4
        for (int jt = 0; jt < 16; ++jt) {
            const bf16x8 pa = *(const bf16x8*)&Pb[r * PSTR + kh * 512 + jt * 32 + kc * 8];
            const bf16x8 vb = *(const bf16x8*)(Vp + jt * 32 + kc * 8);
            acc = __builtin_amdgcn_mfma_f32_16x16x32_bf16(pa, vb, acc, 0, 0, 0);
        }
        __builtin_amdgcn_s_setprio(0);
        if (kh == 1) {
            #pragma unroll
            for (int rr = 0; rr < 4; ++rr)
                part[ct * 272 + (kc * 4 + rr) * 17 + r] = acc[rr];
        }
        __syncthreads();
        if (kh == 0) {
            #pragma unroll
            for (int rr = 0; rr < 4; ++rr) {
                const int row = kc * 4 + rr;
                const float v = (acc[rr] + part[ct * 272 + row * 17 + r]) * invl[row];
                ctxb[((size_t)(b * SEQ) + s0 + row) * DM + h * DH + ct * 16 + r] = (__bf16)v;
            }
        }
    }
}

// ---------------------------------------------------------------------------
// MFMA GEMM (out): 64x128 tiles, 256 blocks (1/CU, was 0.5/CU at 128x128).
// 4 waves, wave tile 32x64 (2x4 fragments). LDS 27.6 KB.
// ---------------------------------------------------------------------------
__global__ __launch_bounds__(256) void gemm_out_mfma(
    const __bf16* __restrict__ ctxb, const __bf16* __restrict__ Wot,
    const float* __restrict__ bo, float* __restrict__ out)
{
    const int t = threadIdx.x;
    const int wave = t >> 6, lane = t & 63;
    const int wm = wave >> 1, wn = wave & 1;
    const int r = lane & 15, kc = lane >> 4, q4 = kc * 4;
    const int lin = blockIdx.x;                              // 0..255
    const int swz = (lin & 7) * 32 + (lin >> 3);             // XCD-contiguous
    const int m0 = (swz >> 2) * 64;
    const int n0 = (swz & 3) * 128;

    __shared__ __align__(16) char smem[27648];
    __bf16* __restrict__ As = (__bf16*)smem;            // [64][72]
    __bf16* __restrict__ Bs = (__bf16*)(smem + 9216);   // [128][72]

    f32x4 acc[2][4];
    #pragma unroll
    for (int i = 0; i < 2; ++i)
        #pragma unroll
        for (int j = 0; j < 4; ++j) acc[i][j] = {0.f, 0.f, 0.f, 0.f};

    const int arow = t >> 2, ack = (t & 3) * 16;   // A stage: 16 elems/thread
    const int brow = t >> 1, bck = (t & 1) * 32;   // B stage: 32 elems/thread
    const __bf16* __restrict__ Ag = ctxb + (size_t)(m0 + arow) * 512 + ack;
    const __bf16* __restrict__ Bg = Wot + (size_t)(n0 + brow) * 512 + bck;

    for (int k0 = 0; k0 < 512; k0 += 64) {
        bf16x8 ra[2], rb[4];
        ra[0] = *(const bf16x8*)(Ag + k0);
        ra[1] = *(const bf16x8*)(Ag + k0 + 8);
        #pragma unroll
        for (int q = 0; q < 4; ++q)
            rb[q] = *(const bf16x8*)(Bg + k0 + q * 8);
        __syncthreads();
        *(bf16x8*)&As[arow * 72 + ack] = ra[0];
        *(bf16x8*)&As[arow * 72 + ack + 8] = ra[1];
        #pragma unroll
        for (int q = 0; q < 4; ++q)
            *(bf16x8*)&Bs[brow * 72 + bck + q * 8] = rb[q];
        __syncthreads();
        #pragma unroll
        for (int ks = 0; ks < 2; ++ks) {
            bf16x8 af[2], bf[4];
            #pragma unroll
            for (int mf = 0; mf < 2; ++mf)
                af[mf] = *(const bf16x8*)&As[(wm * 32 + mf * 16 + r) * 72 + ks * 32 + kc * 8];
            #pragma unroll
            for (int nf = 0; nf < 4; ++nf)
                bf[nf] = *(const bf16x8*)&Bs[(wn * 64 + nf * 16 + r) * 72 + ks * 32 + kc * 8];
            #pragma unroll
            for (int mf = 0; mf < 2; ++mf)
                #pragma unroll
                for (int nf = 0; nf < 4; ++nf)
                    acc[mf][nf] = __builtin_amdgcn_mfma_f32_16x16x32_bf16(
                        af[mf], bf[nf], acc[mf][nf], 0, 0, 0);
        }
    }

    #pragma unroll
    for (int mf = 0; mf < 2; ++mf)
        #pragma unroll
        for (int nf = 0; nf < 4; ++nf) {
            const int n_l = wn * 64 + nf * 16 + r;
            const float bb = bo[n0 + n_l];
            #pragma unroll
            for (int rr = 0; rr < 4; ++rr)
                out[(size_t)(m0 + wm * 32 + mf * 16 + q4 + rr) * DM + n0 + n_l] =
                    acc[mf][nf][rr] + bb;
        }
}

// ---------------------------------------------------------------------------
extern "C" void kernel_launch(void* const* d_in, const int* in_sizes, int n_in,
                              void* d_out, int out_size, void* d_ws, size_t ws_size,
                              hipStream_t stream)
{
    const float* x     = (const float*)d_in[0];
    const float* freqs = (const float*)d_in[1];
    const float* Wq    = (const float*)d_in[2];
    const float* bq    = (const float*)d_in[3];
    const float* Wk    = (const float*)d_in[4];
    const float* bk    = (const float*)d_in[5];
    const float* Wv    = (const float*)d_in[6];
    const float* bv    = (const float*)d_in[7];
    const float* Wo    = (const float*)d_in[8];
    const float* bo    = (const float*)d_in[9];
    const float* W1    = (const float*)d_in[10];
    const float* b1    = (const float*)d_in[11];
    const float* W2    = (const float*)d_in[12];
    // b2 (d_in[13]) is softmax-invariant: dropped.

    char* wsb = (char*)d_ws;
    __bf16* Qb    = (__bf16*)(wsb + QB_OFF);
    __bf16* Kb    = (__bf16*)(wsb + KB_OFF);
    __bf16* Vtb   = (__bf16*)(wsb + VT_OFF);
    __bf16* xb    = (__bf16*)(wsb + XB_OFF);
    __bf16* Wt    = (__bf16*)(wsb + WT_OFF);
    __bf16* Wot   = (__bf16*)(wsb + WOT_OFF);
    __bf16* W2t   = (__bf16*)(wsb + W2T_OFF);
    float*  Aw    = (float*)(wsb + AW_OFF);
    float*  Cw    = (float*)(wsb + CW_OFF);
    __bf16* ctxb  = (__bf16*)(wsb + CTXB_OFF);
    __bf16* biasb = (__bf16*)(wsb + BIAS_OFF);
    float* out = (float*)d_out;

    prologue<<<dim3(2304), 256, 0, stream>>>(
        x, Wq, Wk, Wv, Wo, freqs, W1, b1, W2, xb, Wt, Wot, Aw, Cw, W2t);
    mid_fused<<<dim3(1408), 256, 0, stream>>>(
        xb, Wt, bq, bk, bv, Qb, Kb, Vtb, Aw, Cw, W2t, biasb);
    attn_mfma<<<dim3(2048), 512, 0, stream>>>(Qb, Kb, Vtb, biasb, ctxb);
    gemm_out_mfma<<<dim3(256), 256, 0, stream>>>(ctxb, Wot, bo, out);
}